// Round 1
// baseline (2929.698 us; speedup 1.0000x reference)
//
#include <hip/hip_runtime.h>
#include <math.h>

// ---------------------------------------------------------------------------
// PINN beam loss via forward-mode bivariate jets.
// Jet: f(z + t*(1,1) + s*(1,0)) truncated to t^(NA-1), s^1*t^(NB-1).
//   a[k] = coeff of t^k      (D^k f = k! a[k],  D = d/dx + d/da)
//   b[k] = coeff of t^k s    (dx D^k f = k! b[k])
// ---------------------------------------------------------------------------

__device__ __forceinline__ float fast_tanh(float x) {
    float ax = fabsf(x);
    float e  = __expf(-2.0f * ax);          // exp(-2|x|) in (0,1]
    float y  = (1.0f - e) * __builtin_amdgcn_rcpf(1.0f + e);
    return copysignf(y, x);
}

// tanh of a jet: y = tanh(p), r = q * (1 - y^2)   (s-part chain rule)
// recurrence: (k+1) y_{k+1} = sum_{j=0..k} u_j * (k+1-j) * p_{k+1-j},
//             u = 1 - y^2.
template<int NA, int NB>
__device__ __forceinline__ void tanh_jet(const float (&p)[NA], const float (&q)[NB],
                                         float (&y)[NA], float (&r)[NB]) {
    constexpr int NU = ((NA - 1) > NB ? (NA - 1) : NB);
    float u[NU];
    y[0] = fast_tanh(p[0]);
    u[0] = fmaf(-y[0], y[0], 1.0f);
    if constexpr (NA >= 2) y[1] = u[0] * p[1];
    if constexpr (NU >= 2) u[1] = -2.0f * y[0] * y[1];
    if constexpr (NA >= 3) y[2] = fmaf(u[0], p[2], 0.5f * u[1] * p[1]);
    if constexpr (NU >= 3) u[2] = -fmaf(2.0f * y[0], y[2], y[1] * y[1]);
    if constexpr (NA >= 4) y[3] = fmaf(u[0], p[3], fmaf((2.0f/3.0f) * u[1], p[2],
                                       (1.0f/3.0f) * u[2] * p[1]));
    if constexpr (NU >= 4) u[3] = -2.0f * fmaf(y[0], y[3], y[1] * y[2]);
    if constexpr (NA >= 5) y[4] = fmaf(u[0], p[4], fmaf(0.75f * u[1], p[3],
                                       fmaf(0.5f * u[2], p[2], 0.25f * u[3] * p[1])));
    #pragma unroll
    for (int k = 0; k < NB; ++k) {
        float s = 0.0f;
        #pragma unroll
        for (int j = 0; j <= k; ++j) s = fmaf(u[j], q[k - j], s);
        r[k] = s;
    }
}

// TYPE: 0 = interior (x = input, pde term), 1 = left (x=0), 2 = right (x=L=1)
template<int NA, int NB, int TYPE>
__global__ __launch_bounds__(64)
void pinn_eval(const float* __restrict__ inp,
               const float* __restrict__ W1, const float* __restrict__ b1,
               const float* __restrict__ W2, const float* __restrict__ b2,
               const float* __restrict__ W3, const float* __restrict__ b3,
               const float* __restrict__ W4, const float* __restrict__ b4,
               float* __restrict__ ws, int N, int G)
{
    constexpr int JS  = NA + NB;
    constexpr int JSP = (JS + 1) & ~1;        // even stride -> 8B aligned jets
    constexpr int ST1 = 512 * JSP + 4;        // +4 keeps the two samples' reads
    constexpr int ST2 = 128 * JSP + 4;        //   on disjoint LDS banks
    __shared__ float h1[2 * ST1];
    __shared__ float h2[2 * ST2];

    const int lane = threadIdx.x;
    const int s    = lane >> 5;               // which sample of the pair
    const int g    = lane & 31;
    const int i    = blockIdx.x * 2 + s;
    const bool valid = (i < N);
    const int ii   = valid ? i : (N - 1);

    const float a_in = inp[2 * ii + 1];
    float x_in;
    if constexpr (TYPE == 0)      x_in = inp[2 * ii + 0];
    else if constexpr (TYPE == 1) x_in = 0.0f;
    else                          x_in = 1.0f;   // L = 1

    // ---------------- layer 1: 2 -> 512 ----------------
    // pre-activation jet is sparse: a0 = w_x*x + w_a*a + b, a1 = w_x + w_a, b0 = w_x
    #pragma unroll 4
    for (int j = 0; j < 16; ++j) {
        const int n = g + 32 * j;
        const float w1x = W1[n];
        const float w1a = W1[512 + n];
        float p[NA], q[NB];
        #pragma unroll
        for (int c = 0; c < NA; ++c) p[c] = 0.0f;
        #pragma unroll
        for (int c = 0; c < NB; ++c) q[c] = 0.0f;
        p[0] = fmaf(w1x, x_in, fmaf(w1a, a_in, b1[n]));
        if constexpr (NA >= 2) p[1] = w1x + w1a;
        q[0] = w1x;
        float y[NA], r[NB];
        tanh_jet<NA, NB>(p, q, y, r);
        float* dst = &h1[s * ST1 + n * JSP];
        #pragma unroll
        for (int c = 0; c < NA; ++c) dst[c] = y[c];
        #pragma unroll
        for (int c = 0; c < NB; ++c) dst[NA + c] = r[c];
    }
    __syncthreads();

    // ---------------- layer 2: 512 -> 128 ----------------
    float acc[4][JS];
    #pragma unroll
    for (int j = 0; j < 4; ++j)
        #pragma unroll
        for (int c = 0; c < JS; ++c) acc[j][c] = 0.0f;

    {
        const float* h1s = &h1[s * ST1];
        #pragma unroll 2
        for (int k = 0; k < 512; ++k) {
            float ja[JSP];
            const float2* src = reinterpret_cast<const float2*>(&h1s[k * JSP]);
            #pragma unroll
            for (int c2 = 0; c2 < JSP / 2; ++c2) {
                float2 v = src[c2];
                ja[2 * c2] = v.x; ja[2 * c2 + 1] = v.y;
            }
            const float4 wv = *reinterpret_cast<const float4*>(&W2[k * 128 + 4 * g]);
            const float w[4] = {wv.x, wv.y, wv.z, wv.w};
            #pragma unroll
            for (int j = 0; j < 4; ++j)
                #pragma unroll
                for (int c = 0; c < JS; ++c)
                    acc[j][c] = fmaf(w[j], ja[c], acc[j][c]);
        }
    }
    #pragma unroll
    for (int j = 0; j < 4; ++j) {
        const int n = 4 * g + j;
        float p[NA], q[NB];
        #pragma unroll
        for (int c = 0; c < NA; ++c) p[c] = acc[j][c];
        #pragma unroll
        for (int c = 0; c < NB; ++c) q[c] = acc[j][NA + c];
        p[0] += b2[n];
        float y[NA], r[NB];
        tanh_jet<NA, NB>(p, q, y, r);
        float* dst = &h2[s * ST2 + n * JSP];
        #pragma unroll
        for (int c = 0; c < NA; ++c) dst[c] = y[c];
        #pragma unroll
        for (int c = 0; c < NB; ++c) dst[NA + c] = r[c];
    }
    __syncthreads();

    // ---------------- layer 3: 128 -> 64 ----------------
    float acc3[2][JS];
    #pragma unroll
    for (int j = 0; j < 2; ++j)
        #pragma unroll
        for (int c = 0; c < JS; ++c) acc3[j][c] = 0.0f;
    {
        const float* h2s = &h2[s * ST2];
        #pragma unroll 2
        for (int k = 0; k < 128; ++k) {
            float ja[JSP];
            const float2* src = reinterpret_cast<const float2*>(&h2s[k * JSP]);
            #pragma unroll
            for (int c2 = 0; c2 < JSP / 2; ++c2) {
                float2 v = src[c2];
                ja[2 * c2] = v.x; ja[2 * c2 + 1] = v.y;
            }
            const float2 wv = *reinterpret_cast<const float2*>(&W3[k * 64 + 2 * g]);
            #pragma unroll
            for (int c = 0; c < JS; ++c) {
                acc3[0][c] = fmaf(wv.x, ja[c], acc3[0][c]);
                acc3[1][c] = fmaf(wv.y, ja[c], acc3[1][c]);
            }
        }
    }

    // ---------------- layer 4: 64 -> 1 (per-lane partial + 32-lane reduce) ----
    float part[JS];
    #pragma unroll
    for (int c = 0; c < JS; ++c) part[c] = 0.0f;
    #pragma unroll
    for (int j = 0; j < 2; ++j) {
        const int n = 2 * g + j;
        float p[NA], q[NB];
        #pragma unroll
        for (int c = 0; c < NA; ++c) p[c] = acc3[j][c];
        #pragma unroll
        for (int c = 0; c < NB; ++c) q[c] = acc3[j][NA + c];
        p[0] += b3[n];
        float y[NA], r[NB];
        tanh_jet<NA, NB>(p, q, y, r);
        const float w4 = W4[n];
        #pragma unroll
        for (int c = 0; c < NA; ++c) part[c] = fmaf(w4, y[c], part[c]);
        #pragma unroll
        for (int c = 0; c < NB; ++c) part[NA + c] = fmaf(w4, r[c], part[NA + c]);
    }
    #pragma unroll
    for (int m = 1; m <= 16; m <<= 1)
        #pragma unroll
        for (int c = 0; c < JS; ++c)
            part[c] += __shfl_xor(part[c], m, 64);
    // every lane of each 32-lane half now holds its sample's output jet
    const float A0 = part[0] + b4[0];

    // ---------------- loss terms ----------------
    float t0 = 0.0f, t1 = 0.0f, t2 = 0.0f;
    constexpr float CC = 1.0f;   // P/(E*I)
    if constexpr (TYPE == 0) {
        const float gx = 6.0f * part[NA + 3];          // dx D^3 f
        const float ga = 24.0f * part[4] - gx;         // da D^3 f
        t0 = (gx + CC) * (gx + CC) + (ga + CC) * (ga + CC);
    }
    if constexpr (TYPE == 1) {
        t0 = A0 * A0;                                   // w0^2
        const float gx = part[NA + 0];                  // dx f
        const float ga = part[1] - gx;                  // da f
        t1 = gx * gx + ga * ga;                         // |grad f|^2
    }
    if constexpr (TYPE == 2) {
        const float wa = a_in * A0;
        t0 = wa * wa;                                   // (a*wL)^2
        const float g2x = part[NA + 1];                 // dx D f
        const float g2a = 2.0f * part[2] - g2x;         // da D f
        t1 = g2x * g2x + g2a * g2a;
        const float g3x = 2.0f * part[NA + 2];          // dx D^2 f
        const float g3a = 6.0f * part[3] - g3x;         // da D^2 f
        const float om = 1.0f - a_in;
        t2 = om * om * (g3x * g3x + g3a * g3a);
    }
    if (!valid) { t0 = 0.0f; t1 = 0.0f; t2 = 0.0f; }

    // combine the two samples of the pair, then one write per block
    t0 += __shfl_xor(t0, 32, 64);
    if constexpr (TYPE != 0) t1 += __shfl_xor(t1, 32, 64);
    if constexpr (TYPE == 2) t2 += __shfl_xor(t2, 32, 64);

    if (lane == 0) {
        if constexpr (TYPE == 0) {
            ws[blockIdx.x] = t0;                        // pde
        } else if constexpr (TYPE == 1) {
            ws[G + blockIdx.x]     = t0;                // w0
            ws[2 * G + blockIdx.x] = t1;                // w0_x
        } else {
            ws[3 * G + blockIdx.x] = t0;                // wL
            ws[4 * G + blockIdx.x] = t1;                // wL_xx
            ws[5 * G + blockIdx.x] = t2;                // wL_xxx
        }
    }
}

__global__ __launch_bounds__(1024)
void pinn_reduce(const float* __restrict__ ws, float* __restrict__ out,
                 int G, float invN, float inv2N)
{
    __shared__ float sh[16 * 6];
    float s[6];
    #pragma unroll
    for (int q = 0; q < 6; ++q) {
        float acc = 0.0f;
        for (int i = threadIdx.x; i < G; i += 1024) acc += ws[q * G + i];
        #pragma unroll
        for (int m = 1; m <= 32; m <<= 1) acc += __shfl_xor(acc, m, 64);
        s[q] = acc;
    }
    const int wid = threadIdx.x >> 6;
    if ((threadIdx.x & 63) == 0) {
        #pragma unroll
        for (int q = 0; q < 6; ++q) sh[wid * 6 + q] = s[q];
    }
    __syncthreads();
    if (threadIdx.x == 0) {
        float r[6];
        #pragma unroll
        for (int q = 0; q < 6; ++q) {
            float acc = 0.0f;
            for (int w = 0; w < 16; ++w) acc += sh[w * 6 + q];
            r[q] = acc;
        }
        const float pde   = r[0] * inv2N;
        const float w0    = r[1] * invN;
        const float w0x   = r[2] * inv2N;
        const float wL    = r[3] * invN;
        const float wLxx  = r[4] * inv2N;
        const float wLxxx = r[5] * inv2N;
        out[0] = pde + w0 + w0x + wL + wLxx + wLxxx;
        out[1] = pde;
        out[2] = w0;
        out[3] = w0x;
        out[4] = wL;
        out[5] = wLxx;
        out[6] = wLxxx;
    }
}

extern "C" void kernel_launch(void* const* d_in, const int* in_sizes, int n_in,
                              void* d_out, int out_size, void* d_ws, size_t ws_size,
                              hipStream_t stream) {
    const float* inp = (const float*)d_in[0];
    const float* W1  = (const float*)d_in[1];
    const float* b1  = (const float*)d_in[2];
    const float* W2  = (const float*)d_in[3];
    const float* b2  = (const float*)d_in[4];
    const float* W3  = (const float*)d_in[5];
    const float* b3  = (const float*)d_in[6];
    const float* W4  = (const float*)d_in[7];
    const float* b4  = (const float*)d_in[8];
    float* ws  = (float*)d_ws;
    float* out = (float*)d_out;

    const int N = in_sizes[0] / 2;      // 32768
    const int G = (N + 1) / 2;          // sample pairs per eval type

    // interior: needs grad(D^3 f) -> jet (NA=5, NB=4)
    pinn_eval<5, 4, 0><<<dim3(G), dim3(64), 0, stream>>>(inp, W1, b1, W2, b2, W3, b3, W4, b4, ws, N, G);
    // left x=0: needs f, grad f -> jet (2,1)
    pinn_eval<2, 1, 1><<<dim3(G), dim3(64), 0, stream>>>(inp, W1, b1, W2, b2, W3, b3, W4, b4, ws, N, G);
    // right x=L: needs f, grad(Df), grad(D^2 f) -> jet (4,3)
    pinn_eval<4, 3, 2><<<dim3(G), dim3(64), 0, stream>>>(inp, W1, b1, W2, b2, W3, b3, W4, b4, ws, N, G);

    pinn_reduce<<<dim3(1), dim3(1024), 0, stream>>>(ws, out, G, 1.0f / (float)N, 0.5f / (float)N);
}

// Round 2
// 1664.742 us; speedup vs baseline: 1.7599x; 1.7599x over previous
//
#include <hip/hip_runtime.h>
#include <math.h>

// ---------------------------------------------------------------------------
// PINN beam loss via forward-mode bivariate jets (v2: occupancy-optimized).
// Jet of f(z + t*(1,1) + s*(1,0)):  a[k]=coeff t^k, b[k]=coeff t^k s.
// Layer-1 trick: pre-act = c + d*t + wx*s  =>  b-part derivable from a-part:
//   r[k] = (wx/d)*(k+1)*y[k+1].  Store [y0..y_{NA-1}, e=wx/d] only.
// ---------------------------------------------------------------------------

#define SST 1540   // per-sample LDS float stride (1536 data + 4 bank skew)

__device__ __forceinline__ float fast_tanh(float x) {
    float ax = fabsf(x);
    float e  = __expf(-2.0f * ax);
    float y  = (1.0f - e) * __builtin_amdgcn_rcpf(1.0f + e);
    return copysignf(y, x);
}

// full jet tanh (for layers >= 2 where the s-part is independent)
template<int NA, int NB>
__device__ __forceinline__ void tanh_jet(const float (&p)[NA], const float (&q)[NB],
                                         float (&y)[NA], float (&r)[NB]) {
    constexpr int NU = ((NA - 1) > NB ? (NA - 1) : NB);
    float u[NU];
    y[0] = fast_tanh(p[0]);
    u[0] = fmaf(-y[0], y[0], 1.0f);
    if constexpr (NA >= 2) y[1] = u[0] * p[1];
    if constexpr (NU >= 2) u[1] = -2.0f * y[0] * y[1];
    if constexpr (NA >= 3) y[2] = fmaf(u[0], p[2], 0.5f * u[1] * p[1]);
    if constexpr (NU >= 3) u[2] = -fmaf(2.0f * y[0], y[2], y[1] * y[1]);
    if constexpr (NA >= 4) y[3] = fmaf(u[0], p[3], fmaf((2.0f/3.0f) * u[1], p[2],
                                       (1.0f/3.0f) * u[2] * p[1]));
    if constexpr (NU >= 4) u[3] = -2.0f * fmaf(y[0], y[3], y[1] * y[2]);
    if constexpr (NA >= 5) y[4] = fmaf(u[0], p[4], fmaf(0.75f * u[1], p[3],
                                       fmaf(0.5f * u[2], p[2], 0.25f * u[3] * p[1])));
    #pragma unroll
    for (int k = 0; k < NB; ++k) {
        float s = 0.0f;
        #pragma unroll
        for (int j = 0; j <= k; ++j) s = fmaf(u[j], q[k - j], s);
        r[k] = s;
    }
}

template<int NA, int NB, int TYPE>
__device__ __forceinline__ void eval_body(
    int bi, const float* __restrict__ inp,
    const float* __restrict__ W1, const float* __restrict__ b1,
    const float* __restrict__ W2, const float* __restrict__ b2,
    const float* __restrict__ W3, const float* __restrict__ b3,
    const float* __restrict__ W4, const float* __restrict__ b4,
    float* __restrict__ ws, int N, int NB0, float* h, float (*red)[3])
{
    constexpr int JS  = NA + NB;
    constexpr int JSP = (JS + 1) & ~1;        // h2 jet stride (even)
    constexpr int JST = (NA + 2) & ~1;        // h1 store stride: even(NA+1)

    const int t  = threadIdx.x;
    const int wv = t >> 6;
    const int s  = t >> 5;                    // sample in block (0..3)
    const int g  = t & 31;
    const int i  = bi * 4 + s;
    const bool valid = (i < N);
    const int ii = valid ? i : (N - 1);

    const float a_in = inp[2 * ii + 1];
    float x_in;
    if constexpr (TYPE == 0)      x_in = inp[2 * ii + 0];
    else if constexpr (TYPE == 1) x_in = 0.0f;
    else                          x_in = 1.0f;

    float* hs = h + s * SST;

    // ---------------- layers 1+2 fused, two K-passes of 256 ----------------
    float acc_a[4][NA];
    float acc_bp[4][NB];
    #pragma unroll
    for (int j = 0; j < 4; ++j) {
        #pragma unroll
        for (int c = 0; c < NA; ++c) acc_a[j][c] = 0.0f;
        #pragma unroll
        for (int c = 0; c < NB; ++c) acc_bp[j][c] = 0.0f;
    }

    for (int p = 0; p < 2; ++p) {
        // layer 1: 256 neurons -> [y0..y_{NA-1}, e]
        #pragma unroll
        for (int j = 0; j < 8; ++j) {
            const int kl = g + 32 * j;
            const int nn = p * 256 + kl;
            const float wx = W1[nn];
            const float wa = W1[512 + nn];
            float d = wx + wa;
            if (d == 0.0f) d = 1e-30f;
            const float p0 = fmaf(wx, x_in, fmaf(wa, a_in, b1[nn]));
            const float y0 = fast_tanh(p0);
            const float u0 = fmaf(-y0, y0, 1.0f);
            const float e  = wx * __builtin_amdgcn_rcpf(d);
            float* dst = hs + kl * JST;
            dst[0] = y0;
            float y1 = 0.0f, y2 = 0.0f, y3 = 0.0f;
            if constexpr (NA >= 2) { y1 = u0 * d; dst[1] = y1; }
            if constexpr (NA >= 3) { const float u1 = -2.0f * y0 * y1;
                                     y2 = 0.5f * u1 * d; dst[2] = y2; }
            if constexpr (NA >= 4) { const float u2 = -fmaf(2.0f * y0, y2, y1 * y1);
                                     y3 = (1.0f/3.0f) * u2 * d; dst[3] = y3; }
            if constexpr (NA >= 5) { const float u3 = -2.0f * fmaf(y0, y3, y1 * y2);
                                     dst[4] = 0.25f * u3 * d; }
            dst[NA] = e;
        }
        __syncthreads();

        // layer 2 partial: 256 k's
        const float* Wp = W2 + p * 256 * 128 + 4 * g;
        #pragma unroll 4
        for (int k = 0; k < 256; ++k) {
            float tmp[JST];
            const float2* src = reinterpret_cast<const float2*>(hs + k * JST);
            #pragma unroll
            for (int c2 = 0; c2 < JST / 2; ++c2) {
                const float2 v = src[c2];
                tmp[2 * c2] = v.x; tmp[2 * c2 + 1] = v.y;
            }
            const float e = tmp[NA];
            const float4 wv4 = *reinterpret_cast<const float4*>(Wp + k * 128);
            const float w[4] = {wv4.x, wv4.y, wv4.z, wv4.w};
            #pragma unroll
            for (int j = 0; j < 4; ++j) {
                const float we = w[j] * e;
                #pragma unroll
                for (int c = 0; c < NA; ++c)
                    acc_a[j][c] = fmaf(w[j], tmp[c], acc_a[j][c]);
                #pragma unroll
                for (int c = 0; c < NB; ++c)
                    acc_bp[j][c] = fmaf(we, tmp[c + 1], acc_bp[j][c]);
            }
        }
        __syncthreads();
    }

    // ---------------- layer-2 activation -> h2 (reuses h1 space) ----------
    #pragma unroll
    for (int j = 0; j < 4; ++j) {
        const int n2 = 4 * g + j;
        float pj[NA], qj[NB], yj[NA], rj[NB];
        #pragma unroll
        for (int c = 0; c < NA; ++c) pj[c] = acc_a[j][c];
        pj[0] += b2[n2];
        #pragma unroll
        for (int c = 0; c < NB; ++c) qj[c] = acc_bp[j][c] * (float)(c + 1);
        tanh_jet<NA, NB>(pj, qj, yj, rj);
        float* dst = hs + n2 * JSP;
        #pragma unroll
        for (int c = 0; c < NA; ++c) dst[c] = yj[c];
        #pragma unroll
        for (int c = 0; c < NB; ++c) dst[NA + c] = rj[c];
    }
    __syncthreads();

    // ---------------- layer 3: 128 -> 64 ----------------
    float acc3[2][JS];
    #pragma unroll
    for (int j = 0; j < 2; ++j)
        #pragma unroll
        for (int c = 0; c < JS; ++c) acc3[j][c] = 0.0f;
    {
        const float* W3g = W3 + 2 * g;
        #pragma unroll 2
        for (int k = 0; k < 128; ++k) {
            float ja[JSP];
            const float2* src = reinterpret_cast<const float2*>(hs + k * JSP);
            #pragma unroll
            for (int c2 = 0; c2 < JSP / 2; ++c2) {
                const float2 v = src[c2];
                ja[2 * c2] = v.x; ja[2 * c2 + 1] = v.y;
            }
            const float2 w2v = *reinterpret_cast<const float2*>(W3g + k * 64);
            #pragma unroll
            for (int c = 0; c < JS; ++c) {
                acc3[0][c] = fmaf(w2v.x, ja[c], acc3[0][c]);
                acc3[1][c] = fmaf(w2v.y, ja[c], acc3[1][c]);
            }
        }
    }

    // ---------------- layer 4 + loss ----------------
    float part[JS];
    #pragma unroll
    for (int c = 0; c < JS; ++c) part[c] = 0.0f;
    #pragma unroll
    for (int j = 0; j < 2; ++j) {
        const int n3 = 2 * g + j;
        float pj[NA], qj[NB], yj[NA], rj[NB];
        #pragma unroll
        for (int c = 0; c < NA; ++c) pj[c] = acc3[j][c];
        pj[0] += b3[n3];
        #pragma unroll
        for (int c = 0; c < NB; ++c) qj[c] = acc3[j][NA + c];
        tanh_jet<NA, NB>(pj, qj, yj, rj);
        const float w4 = W4[n3];
        #pragma unroll
        for (int c = 0; c < NA; ++c) part[c] = fmaf(w4, yj[c], part[c]);
        #pragma unroll
        for (int c = 0; c < NB; ++c) part[NA + c] = fmaf(w4, rj[c], part[NA + c]);
    }
    #pragma unroll
    for (int m = 1; m <= 16; m <<= 1)
        #pragma unroll
        for (int c = 0; c < JS; ++c)
            part[c] += __shfl_xor(part[c], m, 64);

    const float A0 = part[0] + b4[0];
    float t0 = 0.0f, t1 = 0.0f, t2 = 0.0f;
    constexpr float CC = 1.0f;   // P/(E*I)
    if constexpr (TYPE == 0) {
        const float gx = 6.0f * part[NA + 3];
        const float ga = 24.0f * part[4] - gx;
        t0 = (gx + CC) * (gx + CC) + (ga + CC) * (ga + CC);
    }
    if constexpr (TYPE == 1) {
        t0 = A0 * A0;
        const float gx = part[NA + 0];
        const float ga = part[1] - gx;
        t1 = gx * gx + ga * ga;
    }
    if constexpr (TYPE == 2) {
        const float wa = a_in * A0;
        t0 = wa * wa;
        const float g2x = part[NA + 1];
        const float g2a = 2.0f * part[2] - g2x;
        t1 = g2x * g2x + g2a * g2a;
        const float g3x = 2.0f * part[NA + 2];
        const float g3a = 6.0f * part[3] - g3x;
        const float om = 1.0f - a_in;
        t2 = om * om * (g3x * g3x + g3a * g3a);
    }
    if (!valid) { t0 = 0.0f; t1 = 0.0f; t2 = 0.0f; }

    // combine the wave's two samples, then the block's two waves
    t0 += __shfl_xor(t0, 32, 64);
    if constexpr (TYPE != 0) t1 += __shfl_xor(t1, 32, 64);
    if constexpr (TYPE == 2) t2 += __shfl_xor(t2, 32, 64);
    if ((t & 63) == 0) { red[wv][0] = t0; red[wv][1] = t1; red[wv][2] = t2; }
    __syncthreads();
    if (t == 0) {
        t0 = red[0][0] + red[1][0];
        t1 = red[0][1] + red[1][1];
        t2 = red[0][2] + red[1][2];
        if constexpr (TYPE == 0) {
            ws[bi] = t0;
        } else if constexpr (TYPE == 1) {
            ws[NB0 + bi]     = t0;
            ws[2 * NB0 + bi] = t1;
        } else {
            ws[3 * NB0 + bi] = t0;
            ws[4 * NB0 + bi] = t1;
            ws[5 * NB0 + bi] = t2;
        }
    }
}

__global__ __launch_bounds__(128, 3)
void pinn_fat(const float* __restrict__ inp,
              const float* __restrict__ W1, const float* __restrict__ b1,
              const float* __restrict__ W2, const float* __restrict__ b2,
              const float* __restrict__ W3, const float* __restrict__ b3,
              const float* __restrict__ W4, const float* __restrict__ b4,
              float* __restrict__ ws, int N, int NB0)
{
    __shared__ float h[4 * SST];
    __shared__ float red[2][3];
    const int b = blockIdx.x;
    if (b < NB0)
        eval_body<5, 4, 0>(b, inp, W1, b1, W2, b2, W3, b3, W4, b4, ws, N, NB0, h, red);
    else if (b < 2 * NB0)
        eval_body<4, 3, 2>(b - NB0, inp, W1, b1, W2, b2, W3, b3, W4, b4, ws, N, NB0, h, red);
    else
        eval_body<2, 1, 1>(b - 2 * NB0, inp, W1, b1, W2, b2, W3, b3, W4, b4, ws, N, NB0, h, red);
}

__global__ __launch_bounds__(1024)
void pinn_reduce(const float* __restrict__ ws, float* __restrict__ out,
                 int G, float invN, float inv2N)
{
    __shared__ float sh[16 * 6];
    float s[6];
    #pragma unroll
    for (int q = 0; q < 6; ++q) {
        float acc = 0.0f;
        for (int i = threadIdx.x; i < G; i += 1024) acc += ws[q * G + i];
        #pragma unroll
        for (int m = 1; m <= 32; m <<= 1) acc += __shfl_xor(acc, m, 64);
        s[q] = acc;
    }
    const int wid = threadIdx.x >> 6;
    if ((threadIdx.x & 63) == 0) {
        #pragma unroll
        for (int q = 0; q < 6; ++q) sh[wid * 6 + q] = s[q];
    }
    __syncthreads();
    if (threadIdx.x == 0) {
        float r[6];
        #pragma unroll
        for (int q = 0; q < 6; ++q) {
            float acc = 0.0f;
            for (int w = 0; w < 16; ++w) acc += sh[w * 6 + q];
            r[q] = acc;
        }
        const float pde   = r[0] * inv2N;
        const float w0    = r[1] * invN;
        const float w0x   = r[2] * inv2N;
        const float wL    = r[3] * invN;
        const float wLxx  = r[4] * inv2N;
        const float wLxxx = r[5] * inv2N;
        out[0] = pde + w0 + w0x + wL + wLxx + wLxxx;
        out[1] = pde;
        out[2] = w0;
        out[3] = w0x;
        out[4] = wL;
        out[5] = wLxx;
        out[6] = wLxxx;
    }
}

extern "C" void kernel_launch(void* const* d_in, const int* in_sizes, int n_in,
                              void* d_out, int out_size, void* d_ws, size_t ws_size,
                              hipStream_t stream) {
    const float* inp = (const float*)d_in[0];
    const float* W1  = (const float*)d_in[1];
    const float* b1  = (const float*)d_in[2];
    const float* W2  = (const float*)d_in[3];
    const float* b2  = (const float*)d_in[4];
    const float* W3  = (const float*)d_in[5];
    const float* b3  = (const float*)d_in[6];
    const float* W4  = (const float*)d_in[7];
    const float* b4  = (const float*)d_in[8];
    float* ws  = (float*)d_ws;
    float* out = (float*)d_out;

    const int N   = in_sizes[0] / 2;   // 32768
    const int NB0 = (N + 3) / 4;       // blocks per eval type (4 samples/block)

    pinn_fat<<<dim3(3 * NB0), dim3(128), 0, stream>>>(
        inp, W1, b1, W2, b2, W3, b3, W4, b4, ws, N, NB0);
    pinn_reduce<<<dim3(1), dim3(1024), 0, stream>>>(
        ws, out, NB0, 1.0f / (float)N, 0.5f / (float)N);
}

// Round 3
// 1569.882 us; speedup vs baseline: 1.8662x; 1.0604x over previous
//
#include <hip/hip_runtime.h>
#include <math.h>

// ---------------------------------------------------------------------------
// PINN beam loss via forward-mode bivariate jets (v3).
// Jet of f(z + t*(1,1) + s*(1,0)):  y[k]=coeff t^k, z[k]=coeff t^k s.
// Layer-1: pre-act = p0 + d*t + wx*s  =>  z[k] = (k+1)*(wx/d)*y[k+1] exactly.
// LDS layout per jet entry: (y0,z0),(y1,z1),...,(y_{NB-1},z_{NB-1}),(y_{NA-1},pad)
//   -> JSP = JS+1 floats (even), pure float2 broadcast reads, pure FMA loops.
// Layer-1 staged in 4 chunks of 128 neurons; h2 overlays the same buffer.
// Per-sample LDS = 1280 floats; 4 samples/block = 20480 B -> 8 blocks/CU.
// ---------------------------------------------------------------------------

#define SST 1280   // per-sample LDS float stride (128 * 10, TYPE0 worst case)

__device__ __forceinline__ float fast_tanh(float x) {
    float ax = fabsf(x);
    float e  = __expf(-2.0f * ax);
    float y  = (1.0f - e) * __builtin_amdgcn_rcpf(1.0f + e);
    return copysignf(y, x);
}

// full jet tanh: y = tanh(p) t-jet, r = s-jet via Leibniz with u = 1 - y^2
template<int NA, int NB>
__device__ __forceinline__ void tanh_jet(const float (&p)[NA], const float (&q)[NB],
                                         float (&y)[NA], float (&r)[NB]) {
    constexpr int NU = ((NA - 1) > NB ? (NA - 1) : NB);
    float u[NU];
    y[0] = fast_tanh(p[0]);
    u[0] = fmaf(-y[0], y[0], 1.0f);
    if constexpr (NA >= 2) y[1] = u[0] * p[1];
    if constexpr (NU >= 2) u[1] = -2.0f * y[0] * y[1];
    if constexpr (NA >= 3) y[2] = fmaf(u[0], p[2], 0.5f * u[1] * p[1]);
    if constexpr (NU >= 3) u[2] = -fmaf(2.0f * y[0], y[2], y[1] * y[1]);
    if constexpr (NA >= 4) y[3] = fmaf(u[0], p[3], fmaf((2.0f/3.0f) * u[1], p[2],
                                       (1.0f/3.0f) * u[2] * p[1]));
    if constexpr (NU >= 4) u[3] = -2.0f * fmaf(y[0], y[3], y[1] * y[2]);
    if constexpr (NA >= 5) y[4] = fmaf(u[0], p[4], fmaf(0.75f * u[1], p[3],
                                       fmaf(0.5f * u[2], p[2], 0.25f * u[3] * p[1])));
    #pragma unroll
    for (int k = 0; k < NB; ++k) {
        float s = 0.0f;
        #pragma unroll
        for (int j = 0; j <= k; ++j) s = fmaf(u[j], q[k - j], s);
        r[k] = s;
    }
}

template<int NA, int NB, int TYPE>
__device__ __forceinline__ void eval_body(
    int bi, const float* __restrict__ inp,
    const float* __restrict__ W1, const float* __restrict__ b1,
    const float* __restrict__ W2, const float* __restrict__ b2,
    const float* __restrict__ W3, const float* __restrict__ b3,
    const float* __restrict__ W4, const float* __restrict__ b4,
    float* __restrict__ ws, int N, int NB0, float* h)
{
    constexpr int JS  = NA + NB;       // 9 / 7 / 3
    constexpr int JSP = JS + 1;        // 10 / 8 / 4  (even)
    constexpr int NP  = JSP / 2;       // float2 pairs per jet

    const int t  = threadIdx.x;
    const int wv = t >> 6;
    const int s  = t >> 5;             // sample in block (0..3)
    const int g  = t & 31;
    const int i  = bi * 4 + s;
    const bool valid = (i < N);
    const int ii = valid ? i : (N - 1);

    const float a_in = inp[2 * ii + 1];
    float x_in;
    if constexpr (TYPE == 0)      x_in = inp[2 * ii + 0];
    else if constexpr (TYPE == 1) x_in = 0.0f;
    else                          x_in = 1.0f;

    float* hs = h + s * SST;

    // ---------------- layers 1+2 fused, four K-chunks of 128 ----------------
    float acc_a[4][NA];
    float acc_b[4][NB];
    #pragma unroll
    for (int j = 0; j < 4; ++j) {
        #pragma unroll
        for (int c = 0; c < NA; ++c) acc_a[j][c] = 0.0f;
        #pragma unroll
        for (int c = 0; c < NB; ++c) acc_b[j][c] = 0.0f;
    }

    for (int ch = 0; ch < 4; ++ch) {
        // layer 1: 128 neurons -> interleaved (y,z) pairs
        #pragma unroll
        for (int j = 0; j < 4; ++j) {
            const int kl = g + 32 * j;
            const int nn = ch * 128 + kl;
            const float wx = W1[nn];
            const float wa = W1[512 + nn];
            float d = wx + wa;
            if (d == 0.0f) d = 1e-30f;
            const float p0 = fmaf(wx, x_in, fmaf(wa, a_in, b1[nn]));
            const float y0 = fast_tanh(p0);
            const float u0 = fmaf(-y0, y0, 1.0f);
            const float e  = wx * __builtin_amdgcn_rcpf(d);
            float* dst = hs + kl * JSP;
            float y1 = 0.0f, y2 = 0.0f, y3 = 0.0f, y4 = 0.0f;
            if constexpr (NA >= 2) y1 = u0 * d;
            if constexpr (NA >= 3) { const float u1 = -2.0f * y0 * y1; y2 = 0.5f * u1 * d; }
            if constexpr (NA >= 4) { const float u2 = -fmaf(2.0f * y0, y2, y1 * y1);
                                     y3 = (1.0f/3.0f) * u2 * d; }
            if constexpr (NA >= 5) { const float u3 = -2.0f * fmaf(y0, y3, y1 * y2);
                                     y4 = 0.25f * u3 * d; }
            // pairs (y[c], z[c]=(c+1)*e*y[c+1]) for c<NB, then (y[NA-1], pad)
            dst[0] = y0;
            dst[1] = e * y1;                       // z0
            if constexpr (NB >= 2) { dst[2] = y1; dst[3] = 2.0f * e * y2; }
            if constexpr (NB >= 3) { dst[4] = y2; dst[5] = 3.0f * e * y3; }
            if constexpr (NB >= 4) { dst[6] = y3; dst[7] = 4.0f * e * y4; }
            dst[2 * NB]     = (NA >= 2) ? ((NA == 2) ? y1 : ((NA == 3) ? y2 : ((NA == 4) ? y3 : y4))) : y0;
            dst[2 * NB + 1] = 0.0f;
        }
        __syncthreads();

        // layer 2 partial: 128 k's, pure FMA
        const float* Wp = W2 + ch * 128 * 128 + 4 * g;
        #pragma unroll 4
        for (int k = 0; k < 128; ++k) {
            float ya[NA], za[NB];
            const float2* src = reinterpret_cast<const float2*>(hs + k * JSP);
            #pragma unroll
            for (int c = 0; c < NB; ++c) {
                const float2 v = src[c];
                ya[c] = v.x; za[c] = v.y;
            }
            ya[NA - 1] = src[NP - 1].x;
            const float4 wv4 = *reinterpret_cast<const float4*>(Wp + k * 128);
            const float w[4] = {wv4.x, wv4.y, wv4.z, wv4.w};
            #pragma unroll
            for (int j = 0; j < 4; ++j) {
                #pragma unroll
                for (int c = 0; c < NA; ++c)
                    acc_a[j][c] = fmaf(w[j], ya[c], acc_a[j][c]);
                #pragma unroll
                for (int c = 0; c < NB; ++c)
                    acc_b[j][c] = fmaf(w[j], za[c], acc_b[j][c]);
            }
        }
        __syncthreads();
    }

    // ---------------- layer-2 activation -> h2 (same interleaved layout) ----
    #pragma unroll
    for (int j = 0; j < 4; ++j) {
        const int n2 = 4 * g + j;
        float pj[NA], qj[NB], yj[NA], rj[NB];
        #pragma unroll
        for (int c = 0; c < NA; ++c) pj[c] = acc_a[j][c];
        pj[0] += b2[n2];
        #pragma unroll
        for (int c = 0; c < NB; ++c) qj[c] = acc_b[j][c];
        tanh_jet<NA, NB>(pj, qj, yj, rj);
        float* dst = hs + n2 * JSP;
        #pragma unroll
        for (int c = 0; c < NB; ++c) { dst[2 * c] = yj[c]; dst[2 * c + 1] = rj[c]; }
        dst[2 * NB]     = yj[NA - 1];
        dst[2 * NB + 1] = 0.0f;
    }
    __syncthreads();

    // ---------------- layer 3: 128 -> 64, pure FMA ----------------
    float a3[2][NA], b3a[2][NB];
    #pragma unroll
    for (int j = 0; j < 2; ++j) {
        #pragma unroll
        for (int c = 0; c < NA; ++c) a3[j][c] = 0.0f;
        #pragma unroll
        for (int c = 0; c < NB; ++c) b3a[j][c] = 0.0f;
    }
    {
        const float* W3g = W3 + 2 * g;
        #pragma unroll 4
        for (int k = 0; k < 128; ++k) {
            float ya[NA], za[NB];
            const float2* src = reinterpret_cast<const float2*>(hs + k * JSP);
            #pragma unroll
            for (int c = 0; c < NB; ++c) {
                const float2 v = src[c];
                ya[c] = v.x; za[c] = v.y;
            }
            ya[NA - 1] = src[NP - 1].x;
            const float2 w2v = *reinterpret_cast<const float2*>(W3g + k * 64);
            #pragma unroll
            for (int c = 0; c < NA; ++c) {
                a3[0][c] = fmaf(w2v.x, ya[c], a3[0][c]);
                a3[1][c] = fmaf(w2v.y, ya[c], a3[1][c]);
            }
            #pragma unroll
            for (int c = 0; c < NB; ++c) {
                b3a[0][c] = fmaf(w2v.x, za[c], b3a[0][c]);
                b3a[1][c] = fmaf(w2v.y, za[c], b3a[1][c]);
            }
        }
    }

    // ---------------- layer 4 + loss ----------------
    float part[JS];
    #pragma unroll
    for (int c = 0; c < JS; ++c) part[c] = 0.0f;
    #pragma unroll
    for (int j = 0; j < 2; ++j) {
        const int n3 = 2 * g + j;
        float pj[NA], qj[NB], yj[NA], rj[NB];
        #pragma unroll
        for (int c = 0; c < NA; ++c) pj[c] = a3[j][c];
        pj[0] += b3[n3];
        #pragma unroll
        for (int c = 0; c < NB; ++c) qj[c] = b3a[j][c];
        tanh_jet<NA, NB>(pj, qj, yj, rj);
        const float w4 = W4[n3];
        #pragma unroll
        for (int c = 0; c < NA; ++c) part[c] = fmaf(w4, yj[c], part[c]);
        #pragma unroll
        for (int c = 0; c < NB; ++c) part[NA + c] = fmaf(w4, rj[c], part[NA + c]);
    }
    #pragma unroll
    for (int m = 1; m <= 16; m <<= 1)
        #pragma unroll
        for (int c = 0; c < JS; ++c)
            part[c] += __shfl_xor(part[c], m, 64);

    const float A0 = part[0] + b4[0];
    float t0 = 0.0f, t1 = 0.0f, t2 = 0.0f;
    constexpr float CC = 1.0f;   // P/(E*I)
    if constexpr (TYPE == 0) {
        const float gx = 6.0f * part[NA + 3];
        const float ga = 24.0f * part[4] - gx;
        t0 = (gx + CC) * (gx + CC) + (ga + CC) * (ga + CC);
    }
    if constexpr (TYPE == 1) {
        t0 = A0 * A0;
        const float gx = part[NA + 0];
        const float ga = part[1] - gx;
        t1 = gx * gx + ga * ga;
    }
    if constexpr (TYPE == 2) {
        const float wa = a_in * A0;
        t0 = wa * wa;
        const float g2x = part[NA + 1];
        const float g2a = 2.0f * part[2] - g2x;
        t1 = g2x * g2x + g2a * g2a;
        const float g3x = 2.0f * part[NA + 2];
        const float g3a = 6.0f * part[3] - g3x;
        const float om = 1.0f - a_in;
        t2 = om * om * (g3x * g3x + g3a * g3a);
    }
    if (!valid) { t0 = 0.0f; t1 = 0.0f; t2 = 0.0f; }

    // combine the wave's two samples, then the block's two waves via LDS
    t0 += __shfl_xor(t0, 32, 64);
    if constexpr (TYPE != 0) t1 += __shfl_xor(t1, 32, 64);
    if constexpr (TYPE == 2) t2 += __shfl_xor(t2, 32, 64);
    __syncthreads();                       // h reads done; reuse h[0..7] as red
    if ((t & 63) == 0) { h[wv * 3 + 0] = t0; h[wv * 3 + 1] = t1; h[wv * 3 + 2] = t2; }
    __syncthreads();
    if (t == 0) {
        t0 = h[0] + h[3];
        t1 = h[1] + h[4];
        t2 = h[2] + h[5];
        if constexpr (TYPE == 0) {
            ws[bi] = t0;
        } else if constexpr (TYPE == 1) {
            ws[NB0 + bi]     = t0;
            ws[2 * NB0 + bi] = t1;
        } else {
            ws[3 * NB0 + bi] = t0;
            ws[4 * NB0 + bi] = t1;
            ws[5 * NB0 + bi] = t2;
        }
    }
}

__global__ __launch_bounds__(128, 4)
void pinn_fat(const float* __restrict__ inp,
              const float* __restrict__ W1, const float* __restrict__ b1,
              const float* __restrict__ W2, const float* __restrict__ b2,
              const float* __restrict__ W3, const float* __restrict__ b3,
              const float* __restrict__ W4, const float* __restrict__ b4,
              float* __restrict__ ws, int N, int NB0)
{
    __shared__ float h[4 * SST];           // 20480 B exactly -> 8 blocks/CU
    const int b = blockIdx.x;
    if (b < NB0)
        eval_body<5, 4, 0>(b, inp, W1, b1, W2, b2, W3, b3, W4, b4, ws, N, NB0, h);
    else if (b < 2 * NB0)
        eval_body<4, 3, 2>(b - NB0, inp, W1, b1, W2, b2, W3, b3, W4, b4, ws, N, NB0, h);
    else
        eval_body<2, 1, 1>(b - 2 * NB0, inp, W1, b1, W2, b2, W3, b3, W4, b4, ws, N, NB0, h);
}

__global__ __launch_bounds__(1024)
void pinn_reduce(const float* __restrict__ ws, float* __restrict__ out,
                 int G, float invN, float inv2N)
{
    __shared__ float sh[16 * 6];
    float s[6];
    #pragma unroll
    for (int q = 0; q < 6; ++q) {
        float acc = 0.0f;
        for (int i = threadIdx.x; i < G; i += 1024) acc += ws[q * G + i];
        #pragma unroll
        for (int m = 1; m <= 32; m <<= 1) acc += __shfl_xor(acc, m, 64);
        s[q] = acc;
    }
    const int wid = threadIdx.x >> 6;
    if ((threadIdx.x & 63) == 0) {
        #pragma unroll
        for (int q = 0; q < 6; ++q) sh[wid * 6 + q] = s[q];
    }
    __syncthreads();
    if (threadIdx.x == 0) {
        float r[6];
        #pragma unroll
        for (int q = 0; q < 6; ++q) {
            float acc = 0.0f;
            for (int w = 0; w < 16; ++w) acc += sh[w * 6 + q];
            r[q] = acc;
        }
        const float pde   = r[0] * inv2N;
        const float w0    = r[1] * invN;
        const float w0x   = r[2] * inv2N;
        const float wL    = r[3] * invN;
        const float wLxx  = r[4] * inv2N;
        const float wLxxx = r[5] * inv2N;
        out[0] = pde + w0 + w0x + wL + wLxx + wLxxx;
        out[1] = pde;
        out[2] = w0;
        out[3] = w0x;
        out[4] = wL;
        out[5] = wLxx;
        out[6] = wLxxx;
    }
}

extern "C" void kernel_launch(void* const* d_in, const int* in_sizes, int n_in,
                              void* d_out, int out_size, void* d_ws, size_t ws_size,
                              hipStream_t stream) {
    const float* inp = (const float*)d_in[0];
    const float* W1  = (const float*)d_in[1];
    const float* b1  = (const float*)d_in[2];
    const float* W2  = (const float*)d_in[3];
    const float* b2  = (const float*)d_in[4];
    const float* W3  = (const float*)d_in[5];
    const float* b3  = (const float*)d_in[6];
    const float* W4  = (const float*)d_in[7];
    const float* b4  = (const float*)d_in[8];
    float* ws  = (float*)d_ws;
    float* out = (float*)d_out;

    const int N   = in_sizes[0] / 2;   // 32768
    const int NB0 = (N + 3) / 4;       // blocks per eval type (4 samples/block)

    pinn_fat<<<dim3(3 * NB0), dim3(128), 0, stream>>>(
        inp, W1, b1, W2, b2, W3, b3, W4, b4, ws, N, NB0);
    pinn_reduce<<<dim3(1), dim3(1024), 0, stream>>>(
        ws, out, NB0, 1.0f / (float)N, 0.5f / (float)N);
}